// Round 1
// baseline (363.815 us; speedup 1.0000x reference)
//
#include <hip/hip_runtime.h>
#include <math.h>

#define B_ 4
#define S_ 2048
#define G_ 8
#define D_ 128
#define N_ 64
#define ROWS (B_*S_*G_)      // 65536
#define CH 64                // chunks per sequence
#define CLEN 32              // steps per chunk (CH*CLEN == S_)
#define NCHAIN (B_*G_*N_)    // 2048 scan chains
#define YOFF (ROWS*D_)       // 8388608, offset of y_i plane in out

// ---------------- K1: dt projection -----------------------------------------
// dt[row][o] = clip(exp(sum_d x_cat[row][d]*dt_w[o][d] + dt_b[o]), 1e-4, 2)
// one wave per row; lane covers 2 elements of x_r and 2 of x_i.
__global__ __launch_bounds__(256) void k_dt(const float* __restrict__ xr,
    const float* __restrict__ xi, const float* __restrict__ dtw,
    const float* __restrict__ dtb, float* __restrict__ dt_mag,
    float* __restrict__ dt_ph)
{
    int lane = threadIdx.x & 63;
    int row  = blockIdx.x * 4 + (threadIdx.x >> 6);
    float2 a = ((const float2*)(xr + row * D_))[lane];
    float2 b = ((const float2*)(xi + row * D_))[lane];
    float2 w0a = ((const float2*)(dtw      ))[lane];
    float2 w0b = ((const float2*)(dtw + 128))[lane];
    float2 w1a = ((const float2*)(dtw + 256))[lane];
    float2 w1b = ((const float2*)(dtw + 384))[lane];
    float p0 = a.x*w0a.x + a.y*w0a.y + b.x*w0b.x + b.y*w0b.y;
    float p1 = a.x*w1a.x + a.y*w1a.y + b.x*w1b.x + b.y*w1b.y;
    #pragma unroll
    for (int m = 32; m >= 1; m >>= 1) {
        p0 += __shfl_xor(p0, m);
        p1 += __shfl_xor(p1, m);
    }
    if (lane == 0) {
        float m0 = fminf(fmaxf(__expf(p0 + dtb[0]), 1e-4f), 2.0f);
        float m1 = fminf(fmaxf(__expf(p1 + dtb[1]), 1e-4f), 2.0f);
        dt_mag[row] = m0;
        dt_ph[row]  = m1;
    }
}

// ---------------- K2: Bx = (x_r + i x_i) * (Bw_r + i Bw_i)^T * dt_mag -------
// block=256 (4 waves). wave w owns K-slice d in [32w,32w+32), lane n owns output n.
// Bw slice kept in registers; x rows staged in LDS, read as broadcast b128.
__global__ __launch_bounds__(256) void k_bx(const float* __restrict__ xr,
    const float* __restrict__ xi, const float* __restrict__ bwr,
    const float* __restrict__ bwi, const float* __restrict__ dt_mag,
    float* __restrict__ bxr, float* __restrict__ bxi)
{
    __shared__ float xsr[16 * 128];
    __shared__ float xsi[16 * 128];
    __shared__ float2 red[4][16][64];
    int t = threadIdx.x;
    int w = t >> 6, n = t & 63;
    int dc = w * 32;
    float4 br[8], bi[8];
    {
        const float4* br4 = (const float4*)(bwr + n * D_ + dc);
        const float4* bi4 = (const float4*)(bwi + n * D_ + dc);
        #pragma unroll
        for (int j = 0; j < 8; j++) { br[j] = br4[j]; bi[j] = bi4[j]; }
    }
    int rowBase = blockIdx.x * 64;
    for (int grp = 0; grp < 4; grp++) {
        int R0 = rowBase + grp * 16;
        // stage 16 rows of x_r/x_i (2048 floats each), coalesced float4
        {
            const float4* gxr = (const float4*)(xr + R0 * D_);
            const float4* gxi = (const float4*)(xi + R0 * D_);
            float4* lsr = (float4*)xsr;
            float4* lsi = (float4*)xsi;
            lsr[t] = gxr[t]; lsr[t + 256] = gxr[t + 256];
            lsi[t] = gxi[t]; lsi[t + 256] = gxi[t + 256];
        }
        __syncthreads();
        #pragma unroll
        for (int r = 0; r < 16; r++) {
            float ar = 0.f, ai = 0.f;
            const float4* hr4 = (const float4*)(xsr + r * D_ + dc);
            const float4* hi4 = (const float4*)(xsi + r * D_ + dc);
            #pragma unroll
            for (int j = 0; j < 8; j++) {
                float4 xv = hr4[j], yv = hi4[j];
                const float* xa = (const float*)&xv;
                const float* ya = (const float*)&yv;
                const float* ba = (const float*)&br[j];
                const float* bb = (const float*)&bi[j];
                #pragma unroll
                for (int k = 0; k < 4; k++) {
                    ar = fmaf(xa[k], ba[k], fmaf(-ya[k], bb[k], ar));
                    ai = fmaf(xa[k], bb[k], fmaf( ya[k], ba[k], ai));
                }
            }
            red[w][r][n] = make_float2(ar, ai);
        }
        __syncthreads();
        #pragma unroll
        for (int q = 0; q < 4; q++) {
            int slot = q * 256 + t;
            int r = slot >> 6, nn = slot & 63;
            float2 s0 = red[0][r][nn], s1 = red[1][r][nn];
            float2 s2 = red[2][r][nn], s3 = red[3][r][nn];
            float sr = s0.x + s1.x + s2.x + s3.x;
            float si = s0.y + s1.y + s2.y + s3.y;
            int row = R0 + r;
            float dm = dt_mag[row];
            bxr[row * N_ + nn] = sr * dm;
            bxi[row * N_ + nn] = si * dm;
        }
        __syncthreads();
    }
}

// ---------------- K3: per-chunk transition (A_prod, B_eff) ------------------
// thread = (bg, c, n). Composition: h_out = A*h_in + B (complex).
__global__ __launch_bounds__(256) void k_scanA(const float* __restrict__ dt_mag,
    const float* __restrict__ dt_ph, const float* __restrict__ logAm,
    const float* __restrict__ Aph, const float* __restrict__ bxr,
    const float* __restrict__ bxi, float4* __restrict__ trans)
{
    int tid = blockIdx.x * 256 + threadIdx.x;  // [0, 131072)
    int n  = tid & 63;
    int c  = (tid >> 6) & 63;
    int bg = tid >> 12;          // [0,32)
    int g = bg & 7, b = bg >> 3;
    float nla = -logf(1.0f + __expf(logAm[g * N_ + n]));
    float aph = Aph[g * N_ + n];
    float Ar = 1.f, Ai = 0.f, Br = 0.f, Bi = 0.f;
    int s0 = c * CLEN;
    #pragma unroll 4
    for (int tt = 0; tt < CLEN; tt++) {
        int row = (b * S_ + s0 + tt) * G_ + g;
        float dm = dt_mag[row], dp = dt_ph[row];
        float am  = __expf(dm * nla);
        float ang = dp * aph;
        float cr = am * __cosf(ang), ci = am * __sinf(ang);
        float vr = bxr[row * N_ + n], vi = bxi[row * N_ + n];
        float nAr = cr * Ar - ci * Ai;
        float nAi = cr * Ai + ci * Ar;
        float nBr = cr * Br - ci * Bi + vr;
        float nBi = cr * Bi + ci * Br + vi;
        Ar = nAr; Ai = nAi; Br = nBr; Bi = nBi;
    }
    trans[tid] = make_float4(Ar, Ai, Br, Bi);
}

// ---------------- K4: combine chunk transitions sequentially ----------------
__global__ __launch_bounds__(256) void k_scanB(const float4* __restrict__ trans,
    float2* __restrict__ hstart)
{
    int tid = blockIdx.x * 256 + threadIdx.x;  // [0, 2048)
    int n = tid & 63;
    int bg = tid >> 6;
    float hr = 0.f, hi = 0.f;
    for (int c = 0; c < CH; c++) {
        int idx = (bg * CH + c) * 64 + n;
        hstart[idx] = make_float2(hr, hi);
        float4 T = trans[idx];
        float nr = T.x * hr - T.y * hi + T.z;
        float ni = T.x * hi + T.y * hr + T.w;
        if ((c & 7) == 7) {  // chunk ends at t=(c+1)*32-1; renorm at (t+1)%256==0
            float nrm = sqrtf(nr * nr + ni * ni + 1e-8f);
            float scale = fminf(nrm, 100.0f) / nrm;
            nr *= scale; ni *= scale;
        }
        hr = nr; hi = ni;
    }
}

// ---------------- K5: re-run chunks from exact h_start, store all h ---------
// overwrites bxr/bxi in place with h_r/h_i (same thread reads then writes elem)
__global__ __launch_bounds__(256) void k_scanC(const float* __restrict__ dt_mag,
    const float* __restrict__ dt_ph, const float* __restrict__ logAm,
    const float* __restrict__ Aph, const float2* __restrict__ hstart,
    float* __restrict__ hR, float* __restrict__ hI)
{
    int tid = blockIdx.x * 256 + threadIdx.x;  // [0, 131072)
    int n  = tid & 63;
    int c  = (tid >> 6) & 63;
    int bg = tid >> 12;
    int g = bg & 7, b = bg >> 3;
    float nla = -logf(1.0f + __expf(logAm[g * N_ + n]));
    float aph = Aph[g * N_ + n];
    float2 h0 = hstart[tid];
    float hr = h0.x, hi = h0.y;
    bool renormChunk = ((c & 7) == 7);
    int s0 = c * CLEN;
    #pragma unroll 4
    for (int tt = 0; tt < CLEN; tt++) {
        int row = (b * S_ + s0 + tt) * G_ + g;
        float dm = dt_mag[row], dp = dt_ph[row];
        float am  = __expf(dm * nla);
        float ang = dp * aph;
        float cr = am * __cosf(ang), ci = am * __sinf(ang);
        float vr = hR[row * N_ + n], vi = hI[row * N_ + n];
        float nr = cr * hr - ci * hi + vr;
        float ni = cr * hi + ci * hr + vi;
        if (renormChunk && tt == CLEN - 1) {
            float nrm = sqrtf(nr * nr + ni * ni + 1e-8f);
            float scale = fminf(nrm, 100.0f) / nrm;
            nr *= scale; ni *= scale;
        }
        hr = nr; hi = ni;
        hR[row * N_ + n] = nr;
        hI[row * N_ + n] = ni;
    }
}

// ---------------- K6: y = (h_r + i h_i) * (Cw_r + i Cw_i)^T -----------------
// block=256 (4 waves). wave w owns K-slice n in [16w,16w+16); lane l owns
// outputs d=l and d=l+64. Cw slice in registers; h rows broadcast from LDS.
__global__ __launch_bounds__(256) void k_out(const float* __restrict__ hR,
    const float* __restrict__ hI, const float* __restrict__ cwr,
    const float* __restrict__ cwi, float* __restrict__ out)
{
    __shared__ float hsr[8 * 64];
    __shared__ float hsi[8 * 64];
    __shared__ float4 red[4][8][64];
    int t = threadIdx.x;
    int w = t >> 6, l = t & 63;
    int nb = w * 16;
    float cr0[16], ci0[16], cr1[16], ci1[16];
    #pragma unroll
    for (int j = 0; j < 16; j++) {
        cr0[j] = cwr[l * N_ + nb + j];
        ci0[j] = cwi[l * N_ + nb + j];
        cr1[j] = cwr[(l + 64) * N_ + nb + j];
        ci1[j] = cwi[(l + 64) * N_ + nb + j];
    }
    int rowBase = blockIdx.x * 64;
    for (int grp = 0; grp < 8; grp++) {
        int R0 = rowBase + grp * 8;
        if (t < 128)       ((float4*)hsr)[t]       = ((const float4*)(hR + R0 * N_))[t];
        else               ((float4*)hsi)[t - 128] = ((const float4*)(hI + R0 * N_))[t - 128];
        __syncthreads();
        #pragma unroll
        for (int r = 0; r < 8; r++) {
            float yr0 = 0.f, yi0 = 0.f, yr1 = 0.f, yi1 = 0.f;
            const float4* p4r = (const float4*)(hsr + r * 64 + nb);
            const float4* p4i = (const float4*)(hsi + r * 64 + nb);
            #pragma unroll
            for (int jq = 0; jq < 4; jq++) {
                float4 hrv = p4r[jq], hiv = p4i[jq];
                const float* hra = (const float*)&hrv;
                const float* hia = (const float*)&hiv;
                #pragma unroll
                for (int k = 0; k < 4; k++) {
                    int j = jq * 4 + k;
                    float a = hra[k], bb = hia[k];
                    yr0 = fmaf(a, cr0[j], fmaf(-bb, ci0[j], yr0));
                    yi0 = fmaf(a, ci0[j], fmaf( bb, cr0[j], yi0));
                    yr1 = fmaf(a, cr1[j], fmaf(-bb, ci1[j], yr1));
                    yi1 = fmaf(a, ci1[j], fmaf( bb, cr1[j], yi1));
                }
            }
            red[w][r][l] = make_float4(yr0, yi0, yr1, yi1);
        }
        __syncthreads();
        #pragma unroll
        for (int q = 0; q < 2; q++) {
            int slot = q * 256 + t;
            int r = slot >> 6, ll = slot & 63;
            float4 a = red[0][r][ll], b2 = red[1][r][ll];
            float4 c2 = red[2][r][ll], d2 = red[3][r][ll];
            float syr0 = a.x + b2.x + c2.x + d2.x;
            float syi0 = a.y + b2.y + c2.y + d2.y;
            float syr1 = a.z + b2.z + c2.z + d2.z;
            float syi1 = a.w + b2.w + c2.w + d2.w;
            int row = R0 + r;
            out[row * D_ + ll]            = syr0;
            out[row * D_ + 64 + ll]       = syr1;
            out[YOFF + row * D_ + ll]      = syi0;
            out[YOFF + row * D_ + 64 + ll] = syi1;
        }
        __syncthreads();
    }
}

extern "C" void kernel_launch(void* const* d_in, const int* in_sizes, int n_in,
                              void* d_out, int out_size, void* d_ws, size_t ws_size,
                              hipStream_t stream) {
    (void)in_sizes; (void)n_in; (void)out_size; (void)ws_size;
    const float* xr    = (const float*)d_in[0];
    const float* xi    = (const float*)d_in[1];
    const float* logAm = (const float*)d_in[2];
    const float* Aph   = (const float*)d_in[3];
    const float* bwr   = (const float*)d_in[4];
    const float* bwi   = (const float*)d_in[5];
    const float* cwr   = (const float*)d_in[6];
    const float* cwi   = (const float*)d_in[7];
    const float* dtw   = (const float*)d_in[8];
    const float* dtb   = (const float*)d_in[9];
    float* out = (float*)d_out;
    float* ws  = (float*)d_ws;

    // workspace layout (floats)
    float*  dt_mag = ws;                      // 65536
    float*  dt_ph  = ws + 65536;              // 65536
    float*  bxr    = ws + 131072;             // 4194304 (later h_r)
    float*  bxi    = bxr + 4194304;           // 4194304 (later h_i)
    float4* trans  = (float4*)(ws + 8519680); // 131072 float4
    float2* hstart = (float2*)(ws + 9043968); // 131072 float2
    // total = 9306112 floats = ~35.5 MiB

    hipLaunchKernelGGL(k_dt,    dim3(ROWS / 4), dim3(256), 0, stream,
                       xr, xi, dtw, dtb, dt_mag, dt_ph);
    hipLaunchKernelGGL(k_bx,    dim3(ROWS / 64), dim3(256), 0, stream,
                       xr, xi, bwr, bwi, dt_mag, bxr, bxi);
    hipLaunchKernelGGL(k_scanA, dim3((NCHAIN * CH) / 256), dim3(256), 0, stream,
                       dt_mag, dt_ph, logAm, Aph, bxr, bxi, trans);
    hipLaunchKernelGGL(k_scanB, dim3(NCHAIN / 256), dim3(256), 0, stream,
                       trans, hstart);
    hipLaunchKernelGGL(k_scanC, dim3((NCHAIN * CH) / 256), dim3(256), 0, stream,
                       dt_mag, dt_ph, logAm, Aph, hstart, bxr, bxi);
    hipLaunchKernelGGL(k_out,   dim3(ROWS / 64), dim3(256), 0, stream,
                       bxr, bxi, cwr, cwi, out);
}

// Round 2
// 222.428 us; speedup vs baseline: 1.6356x; 1.6356x over previous
//
#include <hip/hip_runtime.h>
#include <math.h>

#define B_ 4
#define S_ 2048
#define G_ 8
#define D_ 128
#define N_ 64
#define ROWS (B_*S_*G_)      // 65536
#define CH 64
#define CLEN 32
#define NCHAIN (B_*G_*N_)    // 2048
#define YOFF (ROWS*D_)       // 8388608

typedef short bf16x8 __attribute__((ext_vector_type(8)));
typedef float f32x4  __attribute__((ext_vector_type(4)));
#define MFMA16(a,b,c) __builtin_amdgcn_mfma_f32_16x16x32_bf16(a,b,c,0,0,0)

__device__ __forceinline__ unsigned short bf16_rtne(float f) {
    unsigned u = __float_as_uint(f);
    unsigned r = (u + 0x7FFFu + ((u >> 16) & 1u)) >> 16;
    return (unsigned short)r;
}
__device__ __forceinline__ void split_bf16(float f, unsigned short &hi, unsigned short &lo) {
    hi = bf16_rtne(f);
    float hif = __uint_as_float(((unsigned)hi) << 16);
    lo = bf16_rtne(f - hif);
}
// split a float4 into packed hi/lo bf16 uint2 (4 consecutive k-elements)
__device__ __forceinline__ void split4(float4 v, uint2 &hi2, uint2 &lo2) {
    unsigned short h0,h1,h2,h3,l0,l1,l2,l3;
    split_bf16(v.x,h0,l0); split_bf16(v.y,h1,l1);
    split_bf16(v.z,h2,l2); split_bf16(v.w,h3,l3);
    hi2 = make_uint2((unsigned)h0 | ((unsigned)h1<<16), (unsigned)h2 | ((unsigned)h3<<16));
    lo2 = make_uint2((unsigned)l0 | ((unsigned)l1<<16), (unsigned)l2 | ((unsigned)l3<<16));
}
__device__ __forceinline__ float dot4(float4 a, float4 b) {
    return fmaf(a.x,b.x, fmaf(a.y,b.y, fmaf(a.z,b.z, a.w*b.w)));
}

// ============ G1: fused dt-projection + Bx GEMM (split-bf16 MFMA) ===========
// Bx_cat = [x_r,x_i] (M=65536,K=256) x W^T, W[n][k] (N=128): n<64 -> Bx_r,
// n>=64 -> Bx_i.  M-tile=32/block, 4 waves x 32 n each (2 n-tiles), W in regs.
#define G1_LDK 264   // 256 + 8 pad (bf16 elems)
__global__ __launch_bounds__(256, 2) void k_g1(
    const float* __restrict__ xr, const float* __restrict__ xi,
    const float* __restrict__ bwr, const float* __restrict__ bwi,
    const float* __restrict__ dtw, const float* __restrict__ dtb,
    float* __restrict__ bxr, float* __restrict__ bxi,
    float* __restrict__ dt_mag, float* __restrict__ dt_ph)
{
    __shared__ unsigned short Ahi[32 * G1_LDK];
    __shared__ unsigned short Alo[32 * G1_LDK];
    __shared__ float dms[32], dps[32];
    const int t = threadIdx.x;
    const int lane = t & 63, w = t >> 6;
    const int l15 = lane & 15, quad = lane >> 4;

    // ---- W fragments into registers: wave w owns n in [32w, 32w+32) ----
    bf16x8 wh[2][8], wl[2][8];
    #pragma unroll
    for (int nt = 0; nt < 2; nt++) {
        int n = w * 32 + nt * 16 + l15;
        #pragma unroll
        for (int ks = 0; ks < 8; ks++) {
            int k0 = ks * 32 + quad * 8;
            const float* src; float sgn = 1.f;
            if (n < 64) {
                if (k0 < 128) src = bwr + n * 128 + k0;
                else        { src = bwi + n * 128 + (k0 - 128); sgn = -1.f; }
            } else {
                if (k0 < 128) src = bwi + (n - 64) * 128 + k0;
                else          src = bwr + (n - 64) * 128 + (k0 - 128);
            }
            float4 v0 = *(const float4*)src;
            float4 v1 = *(const float4*)(src + 4);
            float vv[8] = {v0.x,v0.y,v0.z,v0.w,v1.x,v1.y,v1.z,v1.w};
            bf16x8 h8, l8;
            #pragma unroll
            for (int j = 0; j < 8; j++) {
                unsigned short hh, ll;
                split_bf16(vv[j] * sgn, hh, ll);
                h8[j] = (short)hh; l8[j] = (short)ll;
            }
            wh[nt][ks] = h8; wl[nt][ks] = l8;
        }
    }

    // ---- stage x tile (32 rows) as hi/lo bf16 + dt partial dots ----
    const int R0 = blockIdx.x * 32;
    const float4* gxr = (const float4*)(xr + R0 * 128);
    const float4* gxi = (const float4*)(xi + R0 * 128);
    const int kq = t & 31, k4 = kq * 4;
    float4 w0r = *(const float4*)(dtw + k4);
    float4 w0i = *(const float4*)(dtw + 128 + k4);
    float4 w1r = *(const float4*)(dtw + 256 + k4);
    float4 w1i = *(const float4*)(dtw + 384 + k4);
    float pm[4], pp[4];
    #pragma unroll
    for (int i = 0; i < 4; i++) {
        int f = t + 256 * i;          // [0,1024) float4s, 32 f4 per row
        int m = f >> 5;               // row in tile
        float4 a = gxr[f];
        float4 b = gxi[f];
        uint2 h2, l2;
        split4(a, h2, l2);
        *(uint2*)&Ahi[m * G1_LDK + k4] = h2;
        *(uint2*)&Alo[m * G1_LDK + k4] = l2;
        split4(b, h2, l2);
        *(uint2*)&Ahi[m * G1_LDK + 128 + k4] = h2;
        *(uint2*)&Alo[m * G1_LDK + 128 + k4] = l2;
        pm[i] = dot4(a, w0r) + dot4(b, w0i);
        pp[i] = dot4(a, w1r) + dot4(b, w1i);
    }
    // 32-lane tree reduction per row
    float b0 = dtb[0], b1 = dtb[1];
    #pragma unroll
    for (int i = 0; i < 4; i++) {
        float vm = pm[i], vp = pp[i];
        #pragma unroll
        for (int msk = 16; msk >= 1; msk >>= 1) {
            vm += __shfl_xor(vm, msk);
            vp += __shfl_xor(vp, msk);
        }
        if ((t & 31) == 0) {
            int m = (t >> 5) + 8 * i;
            float dm = fminf(fmaxf(__expf(vm + b0), 1e-4f), 2.0f);
            float dp = fminf(fmaxf(__expf(vp + b1), 1e-4f), 2.0f);
            dms[m] = dm; dps[m] = dp;
            dt_mag[R0 + m] = dm; dt_ph[R0 + m] = dp;
        }
    }
    __syncthreads();

    // ---- MFMA: 2 m-subtiles x 2 n-tiles x 8 K-steps x 3 (hi/lo split) ----
    f32x4 acc[2][2];
    #pragma unroll
    for (int a = 0; a < 2; a++)
        #pragma unroll
        for (int b = 0; b < 2; b++)
            acc[a][b] = (f32x4){0.f, 0.f, 0.f, 0.f};
    #pragma unroll
    for (int ms = 0; ms < 2; ms++) {
        int arow = (ms * 16 + l15) * G1_LDK + quad * 8;
        #pragma unroll
        for (int ks = 0; ks < 8; ks++) {
            bf16x8 ah = *(const bf16x8*)&Ahi[arow + ks * 32];
            bf16x8 al = *(const bf16x8*)&Alo[arow + ks * 32];
            #pragma unroll
            for (int nt = 0; nt < 2; nt++) {
                acc[ms][nt] = MFMA16(al, wh[nt][ks], acc[ms][nt]);
                acc[ms][nt] = MFMA16(ah, wl[nt][ks], acc[ms][nt]);
                acc[ms][nt] = MFMA16(ah, wh[nt][ks], acc[ms][nt]);
            }
        }
    }

    // ---- scale by dt_mag, store Bx ----
    #pragma unroll
    for (int ms = 0; ms < 2; ms++) {
        #pragma unroll
        for (int nt = 0; nt < 2; nt++) {
            int n = w * 32 + nt * 16 + l15;
            float* dst = (n < 64) ? bxr : bxi;
            int nn = n & 63;
            #pragma unroll
            for (int r = 0; r < 4; r++) {
                int m = ms * 16 + quad * 4 + r;
                dst[(R0 + m) * 64 + nn] = acc[ms][nt][r] * dms[m];
            }
        }
    }
}

// ============ scan kernels (unchanged structure from R1) ====================
__global__ __launch_bounds__(256) void k_scanA(const float* __restrict__ dt_mag,
    const float* __restrict__ dt_ph, const float* __restrict__ logAm,
    const float* __restrict__ Aph, const float* __restrict__ bxr,
    const float* __restrict__ bxi, float4* __restrict__ trans)
{
    int tid = blockIdx.x * 256 + threadIdx.x;
    int n  = tid & 63;
    int c  = (tid >> 6) & 63;
    int bg = tid >> 12;
    int g = bg & 7, b = bg >> 3;
    float nla = -logf(1.0f + __expf(logAm[g * N_ + n]));
    float aph = Aph[g * N_ + n];
    float Ar = 1.f, Ai = 0.f, Br = 0.f, Bi = 0.f;
    int s0 = c * CLEN;
    #pragma unroll 4
    for (int tt = 0; tt < CLEN; tt++) {
        int row = (b * S_ + s0 + tt) * G_ + g;
        float dm = dt_mag[row], dp = dt_ph[row];
        float am  = __expf(dm * nla);
        float ang = dp * aph;
        float cr = am * __cosf(ang), ci = am * __sinf(ang);
        float vr = bxr[row * N_ + n], vi = bxi[row * N_ + n];
        float nAr = cr * Ar - ci * Ai;
        float nAi = cr * Ai + ci * Ar;
        float nBr = cr * Br - ci * Bi + vr;
        float nBi = cr * Bi + ci * Br + vi;
        Ar = nAr; Ai = nAi; Br = nBr; Bi = nBi;
    }
    trans[tid] = make_float4(Ar, Ai, Br, Bi);
}

__global__ __launch_bounds__(256) void k_scanB(const float4* __restrict__ trans,
    float2* __restrict__ hstart)
{
    int tid = blockIdx.x * 256 + threadIdx.x;
    int n = tid & 63;
    int bg = tid >> 6;
    float hr = 0.f, hi = 0.f;
    for (int c = 0; c < CH; c++) {
        int idx = (bg * CH + c) * 64 + n;
        hstart[idx] = make_float2(hr, hi);
        float4 T = trans[idx];
        float nr = T.x * hr - T.y * hi + T.z;
        float ni = T.x * hi + T.y * hr + T.w;
        if ((c & 7) == 7) {
            float nrm = sqrtf(nr * nr + ni * ni + 1e-8f);
            float scale = fminf(nrm, 100.0f) / nrm;
            nr *= scale; ni *= scale;
        }
        hr = nr; hi = ni;
    }
}

__global__ __launch_bounds__(256) void k_scanC(const float* __restrict__ dt_mag,
    const float* __restrict__ dt_ph, const float* __restrict__ logAm,
    const float* __restrict__ Aph, const float2* __restrict__ hstart,
    float* __restrict__ hR, float* __restrict__ hI)
{
    int tid = blockIdx.x * 256 + threadIdx.x;
    int n  = tid & 63;
    int c  = (tid >> 6) & 63;
    int bg = tid >> 12;
    int g = bg & 7, b = bg >> 3;
    float nla = -logf(1.0f + __expf(logAm[g * N_ + n]));
    float aph = Aph[g * N_ + n];
    float2 h0 = hstart[tid];
    float hr = h0.x, hi = h0.y;
    bool renormChunk = ((c & 7) == 7);
    int s0 = c * CLEN;
    #pragma unroll 4
    for (int tt = 0; tt < CLEN; tt++) {
        int row = (b * S_ + s0 + tt) * G_ + g;
        float dm = dt_mag[row], dp = dt_ph[row];
        float am  = __expf(dm * nla);
        float ang = dp * aph;
        float cr = am * __cosf(ang), ci = am * __sinf(ang);
        float vr = hR[row * N_ + n], vi = hI[row * N_ + n];
        float nr = cr * hr - ci * hi + vr;
        float ni = cr * hi + ci * hr + vi;
        if (renormChunk && tt == CLEN - 1) {
            float nrm = sqrtf(nr * nr + ni * ni + 1e-8f);
            float scale = fminf(nrm, 100.0f) / nrm;
            nr *= scale; ni *= scale;
        }
        hr = nr; hi = ni;
        hR[row * N_ + n] = nr;
        hI[row * N_ + n] = ni;
    }
}

// ============ G2: y GEMM (split-bf16 MFMA) ==================================
// y_cat = [h_r,h_i] (M=65536,K=128) x V^T, V[n][k] (N=256): n<128 -> y_r[d=n],
// n>=128 -> y_i[d=n-128].  M-tile=64/block, 4 waves x 64 n each (4 n-tiles).
#define G2_LDK 136   // 128 + 8 pad
__global__ __launch_bounds__(256, 2) void k_g2(
    const float* __restrict__ hR, const float* __restrict__ hI,
    const float* __restrict__ cwr, const float* __restrict__ cwi,
    float* __restrict__ out)
{
    __shared__ unsigned short Ahi[64 * G2_LDK];
    __shared__ unsigned short Alo[64 * G2_LDK];
    const int t = threadIdx.x;
    const int lane = t & 63, w = t >> 6;
    const int l15 = lane & 15, quad = lane >> 4;

    // ---- V fragments into registers: wave w owns n in [64w, 64w+64) ----
    bf16x8 wh[4][4], wl[4][4];
    #pragma unroll
    for (int nt = 0; nt < 4; nt++) {
        int n = w * 64 + nt * 16 + l15;
        int d = (n < 128) ? n : (n - 128);
        #pragma unroll
        for (int ks = 0; ks < 4; ks++) {
            int k0 = ks * 32 + quad * 8;
            const float* src; float sgn = 1.f;
            if (n < 128) {
                if (k0 < 64) src = cwr + d * 64 + k0;
                else       { src = cwi + d * 64 + (k0 - 64); sgn = -1.f; }
            } else {
                if (k0 < 64) src = cwi + d * 64 + k0;
                else         src = cwr + d * 64 + (k0 - 64);
            }
            float4 v0 = *(const float4*)src;
            float4 v1 = *(const float4*)(src + 4);
            float vv[8] = {v0.x,v0.y,v0.z,v0.w,v1.x,v1.y,v1.z,v1.w};
            bf16x8 h8, l8;
            #pragma unroll
            for (int j = 0; j < 8; j++) {
                unsigned short hh, ll;
                split_bf16(vv[j] * sgn, hh, ll);
                h8[j] = (short)hh; l8[j] = (short)ll;
            }
            wh[nt][ks] = h8; wl[nt][ks] = l8;
        }
    }

    // ---- stage h tile (64 rows, K=128) as hi/lo bf16 ----
    const int R0 = blockIdx.x * 64;
    const float4* gr = (const float4*)(hR + R0 * 64);
    const float4* gi = (const float4*)(hI + R0 * 64);
    #pragma unroll
    for (int i = 0; i < 4; i++) {
        int f = t + 256 * i;          // [0,1024), 16 f4 per row
        int m = f >> 4;
        int kk = (f & 15) * 4;
        uint2 h2, l2;
        split4(gr[f], h2, l2);
        *(uint2*)&Ahi[m * G2_LDK + kk] = h2;
        *(uint2*)&Alo[m * G2_LDK + kk] = l2;
        split4(gi[f], h2, l2);
        *(uint2*)&Ahi[m * G2_LDK + 64 + kk] = h2;
        *(uint2*)&Alo[m * G2_LDK + 64 + kk] = l2;
    }
    __syncthreads();

    // ---- MFMA: 4 m-subtiles x 4 n-tiles x 4 K-steps x 3 ----
    f32x4 acc[4][4];
    #pragma unroll
    for (int a = 0; a < 4; a++)
        #pragma unroll
        for (int b = 0; b < 4; b++)
            acc[a][b] = (f32x4){0.f, 0.f, 0.f, 0.f};
    #pragma unroll
    for (int ms = 0; ms < 4; ms++) {
        int arow = (ms * 16 + l15) * G2_LDK + quad * 8;
        #pragma unroll
        for (int ks = 0; ks < 4; ks++) {
            bf16x8 ah = *(const bf16x8*)&Ahi[arow + ks * 32];
            bf16x8 al = *(const bf16x8*)&Alo[arow + ks * 32];
            #pragma unroll
            for (int nt = 0; nt < 4; nt++) {
                acc[ms][nt] = MFMA16(al, wh[nt][ks], acc[ms][nt]);
                acc[ms][nt] = MFMA16(ah, wl[nt][ks], acc[ms][nt]);
                acc[ms][nt] = MFMA16(ah, wh[nt][ks], acc[ms][nt]);
            }
        }
    }

    // ---- store y ----
    #pragma unroll
    for (int ms = 0; ms < 4; ms++) {
        #pragma unroll
        for (int nt = 0; nt < 4; nt++) {
            int n = w * 64 + nt * 16 + l15;
            float* dst = (n < 128) ? (out + n) : (out + YOFF + (n - 128));
            #pragma unroll
            for (int r = 0; r < 4; r++) {
                int m = ms * 16 + quad * 4 + r;
                dst[(R0 + m) * 128] = acc[ms][nt][r];
            }
        }
    }
}

extern "C" void kernel_launch(void* const* d_in, const int* in_sizes, int n_in,
                              void* d_out, int out_size, void* d_ws, size_t ws_size,
                              hipStream_t stream) {
    (void)in_sizes; (void)n_in; (void)out_size; (void)ws_size;
    const float* xr    = (const float*)d_in[0];
    const float* xi    = (const float*)d_in[1];
    const float* logAm = (const float*)d_in[2];
    const float* Aph   = (const float*)d_in[3];
    const float* bwr   = (const float*)d_in[4];
    const float* bwi   = (const float*)d_in[5];
    const float* cwr   = (const float*)d_in[6];
    const float* cwi   = (const float*)d_in[7];
    const float* dtw   = (const float*)d_in[8];
    const float* dtb   = (const float*)d_in[9];
    float* out = (float*)d_out;
    float* ws  = (float*)d_ws;

    float*  dt_mag = ws;                      // 65536
    float*  dt_ph  = ws + 65536;              // 65536
    float*  bxr    = ws + 131072;             // 4194304 (becomes h_r)
    float*  bxi    = bxr + 4194304;           // 4194304 (becomes h_i)
    float4* trans  = (float4*)(ws + 8519680); // 131072 float4
    float2* hstart = (float2*)(ws + 9043968); // 131072 float2

    hipLaunchKernelGGL(k_g1,    dim3(ROWS / 32), dim3(256), 0, stream,
                       xr, xi, bwr, bwi, dtw, dtb, bxr, bxi, dt_mag, dt_ph);
    hipLaunchKernelGGL(k_scanA, dim3((NCHAIN * CH) / 256), dim3(256), 0, stream,
                       dt_mag, dt_ph, logAm, Aph, bxr, bxi, trans);
    hipLaunchKernelGGL(k_scanB, dim3(NCHAIN / 256), dim3(256), 0, stream,
                       trans, hstart);
    hipLaunchKernelGGL(k_scanC, dim3((NCHAIN * CH) / 256), dim3(256), 0, stream,
                       dt_mag, dt_ph, logAm, Aph, hstart, bxr, bxi);
    hipLaunchKernelGGL(k_g2,    dim3(ROWS / 64), dim3(256), 0, stream,
                       bxr, bxi, cwr, cwi, out);
}

// Round 3
// 174.064 us; speedup vs baseline: 2.0901x; 1.2779x over previous
//
#include <hip/hip_runtime.h>
#include <math.h>

#define B_ 4
#define S_ 2048
#define G_ 8
#define D_ 128
#define N_ 64
#define ROWS (B_*S_*G_)      // 65536
#define CH 64
#define CLEN 32
#define NCHAIN (B_*G_*N_)    // 2048
#define YOFF (ROWS*D_)       // 8388608

typedef short bf16x8 __attribute__((ext_vector_type(8)));
typedef float f32x4  __attribute__((ext_vector_type(4)));
#define MFMA16(a,b,c) __builtin_amdgcn_mfma_f32_16x16x32_bf16(a,b,c,0,0,0)

__device__ __forceinline__ unsigned short bf16_rtne(float f) {
    unsigned u = __float_as_uint(f);
    unsigned r = (u + 0x7FFFu + ((u >> 16) & 1u)) >> 16;
    return (unsigned short)r;
}
__device__ __forceinline__ void split_bf16(float f, unsigned short &hi, unsigned short &lo) {
    hi = bf16_rtne(f);
    float hif = __uint_as_float(((unsigned)hi) << 16);
    lo = bf16_rtne(f - hif);
}
__device__ __forceinline__ void split4(float4 v, uint2 &hi2, uint2 &lo2) {
    unsigned short h0,h1,h2,h3,l0,l1,l2,l3;
    split_bf16(v.x,h0,l0); split_bf16(v.y,h1,l1);
    split_bf16(v.z,h2,l2); split_bf16(v.w,h3,l3);
    hi2 = make_uint2((unsigned)h0 | ((unsigned)h1<<16), (unsigned)h2 | ((unsigned)h3<<16));
    lo2 = make_uint2((unsigned)l0 | ((unsigned)l1<<16), (unsigned)l2 | ((unsigned)l3<<16));
}
__device__ __forceinline__ float dot4(float4 a, float4 b) {
    return fmaf(a.x,b.x, fmaf(a.y,b.y, fmaf(a.z,b.z, a.w*b.w)));
}

// ============ k_prep: pre-split weights into MFMA fragment order ============
// g1 W: [w(4)][nt(2)][ks(8)][lane(64)] bf16x8  (hi and lo arrays)
// g2 V: [w(4)][nt(4)][ks(4)][lane(64)] bf16x8  (hi only)
__global__ __launch_bounds__(256) void k_prep(
    const float* __restrict__ bwr, const float* __restrict__ bwi,
    const float* __restrict__ cwr, const float* __restrict__ cwi,
    unsigned short* __restrict__ wbhi, unsigned short* __restrict__ wblo,
    unsigned short* __restrict__ wchi)
{
    int tid = blockIdx.x * 256 + threadIdx.x;   // [0, 8192)
    if (tid < 4096) {
        int f = tid;
        int lane = f & 63, ks = (f >> 6) & 7, nt = (f >> 9) & 1, w = f >> 10;
        int l15 = lane & 15, quad = lane >> 4;
        int n = w * 32 + nt * 16 + l15;
        int k0 = ks * 32 + quad * 8;
        const float* src; float sgn = 1.f;
        if (n < 64) {
            if (k0 < 128) src = bwr + n * 128 + k0;
            else        { src = bwi + n * 128 + (k0 - 128); sgn = -1.f; }
        } else {
            if (k0 < 128) src = bwi + (n - 64) * 128 + k0;
            else          src = bwr + (n - 64) * 128 + (k0 - 128);
        }
        float4 v0 = *(const float4*)src;
        float4 v1 = *(const float4*)(src + 4);
        float vv[8] = {v0.x,v0.y,v0.z,v0.w,v1.x,v1.y,v1.z,v1.w};
        unsigned short h[8], l[8];
        #pragma unroll
        for (int j = 0; j < 8; j++) split_bf16(vv[j] * sgn, h[j], l[j]);
        #pragma unroll
        for (int j = 0; j < 8; j++) { wbhi[f*8+j] = h[j]; wblo[f*8+j] = l[j]; }
    } else {
        int f = tid - 4096;
        int lane = f & 63, ks = (f >> 6) & 3, nt = (f >> 8) & 3, w = f >> 10;
        int l15 = lane & 15, quad = lane >> 4;
        int n = w * 64 + nt * 16 + l15;
        int d = (n < 128) ? n : (n - 128);
        int k0 = ks * 32 + quad * 8;
        const float* src; float sgn = 1.f;
        if (n < 128) {
            if (k0 < 64) src = cwr + d * 64 + k0;
            else       { src = cwi + d * 64 + (k0 - 64); sgn = -1.f; }
        } else {
            if (k0 < 64) src = cwi + d * 64 + k0;
            else         src = cwr + d * 64 + (k0 - 64);
        }
        float4 v0 = *(const float4*)src;
        float4 v1 = *(const float4*)(src + 4);
        float vv[8] = {v0.x,v0.y,v0.z,v0.w,v1.x,v1.y,v1.z,v1.w};
        unsigned short h[8], l[8];
        #pragma unroll
        for (int j = 0; j < 8; j++) split_bf16(vv[j] * sgn, h[j], l[j]);
        #pragma unroll
        for (int j = 0; j < 8; j++) wchi[f*8+j] = h[j];
    }
}

// ============ G1: fused dt + Bx GEMM, weights preloaded, 4 tiles/block ======
// LDS row stride 280 shorts = 560B == 12 banks mod 32 -> 2-way only (free)
#define LDK1 280
__global__ __launch_bounds__(256, 2) void k_g1(
    const float* __restrict__ xr, const float* __restrict__ xi,
    const float* __restrict__ dtw, const float* __restrict__ dtb,
    const unsigned short* __restrict__ wbhi, const unsigned short* __restrict__ wblo,
    float* __restrict__ bxr, float* __restrict__ bxi,
    float* __restrict__ dt_mag, float* __restrict__ dt_ph)
{
    __shared__ __align__(16) unsigned short Ahi[32 * LDK1];
    __shared__ __align__(16) unsigned short Alo[32 * LDK1];
    __shared__ float dms[32];
    const int t = threadIdx.x;
    const int lane = t & 63, w = t >> 6;
    const int l15 = lane & 15, quad = lane >> 4;

    // W fragments (precomputed, coalesced 16B loads)
    bf16x8 wh[2][8], wl[2][8];
    #pragma unroll
    for (int nt = 0; nt < 2; nt++)
        #pragma unroll
        for (int ks = 0; ks < 8; ks++) {
            int idx = ((w * 2 + nt) * 8 + ks) * 64 + lane;
            wh[nt][ks] = ((const bf16x8*)wbhi)[idx];
            wl[nt][ks] = ((const bf16x8*)wblo)[idx];
        }

    const int kq = t & 31, k4 = kq * 4;
    float4 w0r = *(const float4*)(dtw + k4);
    float4 w0i = *(const float4*)(dtw + 128 + k4);
    float4 w1r = *(const float4*)(dtw + 256 + k4);
    float4 w1i = *(const float4*)(dtw + 384 + k4);
    float b0 = dtb[0], b1 = dtb[1];

    for (int it = 0; it < 4; it++) {
        const int R0 = (blockIdx.x * 4 + it) * 32;
        const float4* gxr = (const float4*)(xr + R0 * 128);
        const float4* gxi = (const float4*)(xi + R0 * 128);
        float pm[4], pp[4];
        #pragma unroll
        for (int i = 0; i < 4; i++) {
            int f = t + 256 * i;
            int m = f >> 5;
            float4 a = gxr[f];
            float4 b = gxi[f];
            uint2 h2, l2;
            split4(a, h2, l2);
            *(uint2*)&Ahi[m * LDK1 + k4] = h2;
            *(uint2*)&Alo[m * LDK1 + k4] = l2;
            split4(b, h2, l2);
            *(uint2*)&Ahi[m * LDK1 + 128 + k4] = h2;
            *(uint2*)&Alo[m * LDK1 + 128 + k4] = l2;
            pm[i] = dot4(a, w0r) + dot4(b, w0i);
            pp[i] = dot4(a, w1r) + dot4(b, w1i);
        }
        #pragma unroll
        for (int i = 0; i < 4; i++) {
            float vm = pm[i], vp = pp[i];
            #pragma unroll
            for (int msk = 16; msk >= 1; msk >>= 1) {
                vm += __shfl_xor(vm, msk);
                vp += __shfl_xor(vp, msk);
            }
            if ((t & 31) == 0) {
                int m = (t >> 5) + 8 * i;
                float dm = fminf(fmaxf(__expf(vm + b0), 1e-4f), 2.0f);
                float dp = fminf(fmaxf(__expf(vp + b1), 1e-4f), 2.0f);
                dms[m] = dm;
                dt_mag[R0 + m] = dm; dt_ph[R0 + m] = dp;
            }
        }
        __syncthreads();

        f32x4 acc[2][2];
        #pragma unroll
        for (int a = 0; a < 2; a++)
            #pragma unroll
            for (int b = 0; b < 2; b++)
                acc[a][b] = (f32x4){0.f, 0.f, 0.f, 0.f};
        #pragma unroll
        for (int ms = 0; ms < 2; ms++) {
            int arow = (ms * 16 + l15) * LDK1 + quad * 8;
            #pragma unroll
            for (int ks = 0; ks < 8; ks++) {
                bf16x8 ah = *(const bf16x8*)&Ahi[arow + ks * 32];
                bf16x8 al = *(const bf16x8*)&Alo[arow + ks * 32];
                #pragma unroll
                for (int nt = 0; nt < 2; nt++) {
                    acc[ms][nt] = MFMA16(al, wh[nt][ks], acc[ms][nt]);
                    acc[ms][nt] = MFMA16(ah, wl[nt][ks], acc[ms][nt]);
                    acc[ms][nt] = MFMA16(ah, wh[nt][ks], acc[ms][nt]);
                }
            }
        }
        #pragma unroll
        for (int ms = 0; ms < 2; ms++)
            #pragma unroll
            for (int nt = 0; nt < 2; nt++) {
                int n = w * 32 + nt * 16 + l15;
                float* dst = (n < 64) ? bxr : bxi;
                int nn = n & 63;
                #pragma unroll
                for (int r = 0; r < 4; r++) {
                    int m = ms * 16 + quad * 4 + r;
                    dst[(R0 + m) * 64 + nn] = acc[ms][nt][r] * dms[m];
                }
            }
        __syncthreads();
    }
}

// ============ scanA / scanB (unchanged) =====================================
__global__ __launch_bounds__(256) void k_scanA(const float* __restrict__ dt_mag,
    const float* __restrict__ dt_ph, const float* __restrict__ logAm,
    const float* __restrict__ Aph, const float* __restrict__ bxr,
    const float* __restrict__ bxi, float4* __restrict__ trans)
{
    int tid = blockIdx.x * 256 + threadIdx.x;
    int n  = tid & 63;
    int c  = (tid >> 6) & 63;
    int bg = tid >> 12;
    int g = bg & 7, b = bg >> 3;
    float nla = -logf(1.0f + __expf(logAm[g * N_ + n]));
    float aph = Aph[g * N_ + n];
    float Ar = 1.f, Ai = 0.f, Br = 0.f, Bi = 0.f;
    int s0 = c * CLEN;
    #pragma unroll 4
    for (int tt = 0; tt < CLEN; tt++) {
        int row = (b * S_ + s0 + tt) * G_ + g;
        float dm = dt_mag[row], dp = dt_ph[row];
        float am  = __expf(dm * nla);
        float ang = dp * aph;
        float cr = am * __cosf(ang), ci = am * __sinf(ang);
        float vr = bxr[row * N_ + n], vi = bxi[row * N_ + n];
        float nAr = cr * Ar - ci * Ai;
        float nAi = cr * Ai + ci * Ar;
        float nBr = cr * Br - ci * Bi + vr;
        float nBi = cr * Bi + ci * Br + vi;
        Ar = nAr; Ai = nAi; Br = nBr; Bi = nBi;
    }
    trans[tid] = make_float4(Ar, Ai, Br, Bi);
}

__global__ __launch_bounds__(256) void k_scanB(const float4* __restrict__ trans,
    float2* __restrict__ hstart)
{
    int tid = blockIdx.x * 256 + threadIdx.x;
    int n = tid & 63;
    int bg = tid >> 6;
    float hr = 0.f, hi = 0.f;
    for (int c = 0; c < CH; c++) {
        int idx = (bg * CH + c) * 64 + n;
        hstart[idx] = make_float2(hr, hi);
        float4 T = trans[idx];
        float nr = T.x * hr - T.y * hi + T.z;
        float ni = T.x * hi + T.y * hr + T.w;
        if ((c & 7) == 7) {
            float nrm = sqrtf(nr * nr + ni * ni + 1e-8f);
            float scale = fminf(nrm, 100.0f) / nrm;
            nr *= scale; ni *= scale;
        }
        hr = nr; hi = ni;
    }
}

// ============ SG2: fused scanC + y GEMM =====================================
// block = (bg, cq): wave w scans chunk cq*4+w (32 steps, lane = n), stages h
// as split-bf16 directly into LDS fragment tiles; then M=128 x N=256 x K=128
// GEMM in two M=64 halves. 2-MFMA: (A_hi + A_lo) x W_hi.
#define LDK2 152
__global__ __launch_bounds__(256, 2) void k_sg2(
    const float* __restrict__ bxr, const float* __restrict__ bxi,
    const float* __restrict__ dt_mag, const float* __restrict__ dt_ph,
    const float* __restrict__ logAm, const float* __restrict__ Aph,
    const float2* __restrict__ hstart,
    const unsigned short* __restrict__ wchi,
    float* __restrict__ out)
{
    __shared__ __align__(16) unsigned short Ahi[128 * LDK2];
    __shared__ __align__(16) unsigned short Alo[128 * LDK2];
    const int t = threadIdx.x;
    const int lane = t & 63, w = t >> 6;
    const int l15 = lane & 15, quad = lane >> 4;
    const int bg = blockIdx.x >> 4, cq = blockIdx.x & 15;
    const int g = bg & 7, b = bg >> 3;

    // V fragments (hi only)
    bf16x8 wc[4][4];
    #pragma unroll
    for (int nt = 0; nt < 4; nt++)
        #pragma unroll
        for (int ks = 0; ks < 4; ks++)
            wc[nt][ks] = ((const bf16x8*)wchi)[((w * 4 + nt) * 4 + ks) * 64 + lane];

    // ---- scan phase: wave w owns chunk c = cq*4 + w, lane = n ----
    {
        const int n = lane;
        const int c = cq * 4 + w;
        float nla = -logf(1.0f + __expf(logAm[g * N_ + n]));
        float aph = Aph[g * N_ + n];
        float2 h0 = hstart[(bg * CH + c) * 64 + n];
        float hr = h0.x, hi = h0.y;
        const bool rn = ((c & 7) == 7);
        const int rowbase = (b * S_ + c * CLEN) * G_ + g;
        #pragma unroll 8
        for (int tt = 0; tt < CLEN; tt++) {
            int row = rowbase + tt * G_;
            float dm = dt_mag[row], dp = dt_ph[row];
            float am  = __expf(dm * nla);
            float ang = dp * aph;
            float cr = am * __cosf(ang), ci = am * __sinf(ang);
            float vr = bxr[row * N_ + n], vi = bxi[row * N_ + n];
            float nr = cr * hr - ci * hi + vr;
            float ni = cr * hi + ci * hr + vi;
            if (rn && tt == CLEN - 1) {
                float nrm = sqrtf(nr * nr + ni * ni + 1e-8f);
                float scale = fminf(nrm, 100.0f) / nrm;
                nr *= scale; ni *= scale;
            }
            hr = nr; hi = ni;
            int m = w * 32 + tt;
            unsigned short hh, hl;
            split_bf16(hr, hh, hl);
            Ahi[m * LDK2 + n] = hh;  Alo[m * LDK2 + n] = hl;
            split_bf16(hi, hh, hl);
            Ahi[m * LDK2 + 64 + n] = hh;  Alo[m * LDK2 + 64 + n] = hl;
        }
    }
    __syncthreads();

    // ---- GEMM phase: two M=64 halves ----
    #pragma unroll
    for (int mh = 0; mh < 2; mh++) {
        f32x4 acc[4][4];
        #pragma unroll
        for (int a = 0; a < 4; a++)
            #pragma unroll
            for (int bq = 0; bq < 4; bq++)
                acc[a][bq] = (f32x4){0.f, 0.f, 0.f, 0.f};
        #pragma unroll
        for (int ms = 0; ms < 4; ms++) {
            int arow = (mh * 64 + ms * 16 + l15) * LDK2 + quad * 8;
            #pragma unroll
            for (int ks = 0; ks < 4; ks++) {
                bf16x8 ah = *(const bf16x8*)&Ahi[arow + ks * 32];
                bf16x8 al = *(const bf16x8*)&Alo[arow + ks * 32];
                #pragma unroll
                for (int nt = 0; nt < 4; nt++) {
                    acc[ms][nt] = MFMA16(al, wc[nt][ks], acc[ms][nt]);
                    acc[ms][nt] = MFMA16(ah, wc[nt][ks], acc[ms][nt]);
                }
            }
        }
        #pragma unroll
        for (int ms = 0; ms < 4; ms++)
            #pragma unroll
            for (int nt = 0; nt < 4; nt++) {
                int nn = w * 64 + nt * 16 + l15;
                float* dst = (nn < 128) ? (out + nn) : (out + YOFF + (nn - 128));
                #pragma unroll
                for (int r = 0; r < 4; r++) {
                    int m_local = mh * 64 + ms * 16 + quad * 4 + r;
                    int cc = m_local >> 5, tt2 = m_local & 31;
                    int srow = (b * S_ + (cq * 4 + cc) * CLEN + tt2) * G_ + g;
                    dst[srow * 128] = acc[ms][nt][r];
                }
            }
    }
}

extern "C" void kernel_launch(void* const* d_in, const int* in_sizes, int n_in,
                              void* d_out, int out_size, void* d_ws, size_t ws_size,
                              hipStream_t stream) {
    (void)in_sizes; (void)n_in; (void)out_size; (void)ws_size;
    const float* xr    = (const float*)d_in[0];
    const float* xi    = (const float*)d_in[1];
    const float* logAm = (const float*)d_in[2];
    const float* Aph   = (const float*)d_in[3];
    const float* bwr   = (const float*)d_in[4];
    const float* bwi   = (const float*)d_in[5];
    const float* cwr   = (const float*)d_in[6];
    const float* cwi   = (const float*)d_in[7];
    const float* dtw   = (const float*)d_in[8];
    const float* dtb   = (const float*)d_in[9];
    float* out = (float*)d_out;
    float* ws  = (float*)d_ws;

    float*  dt_mag = ws;                      // 65536
    float*  dt_ph  = ws + 65536;              // 65536
    float*  bxr    = ws + 131072;             // 4194304
    float*  bxi    = bxr + 4194304;           // 4194304
    float4* trans  = (float4*)(ws + 8519680); // 131072 float4
    float2* hstart = (float2*)(ws + 9043968); // 131072 float2
    unsigned short* wbhi = (unsigned short*)(ws + 9306112); // 32768 shorts
    unsigned short* wblo = wbhi + 32768;
    unsigned short* wchi = wblo + 32768;

    hipLaunchKernelGGL(k_prep,  dim3(32), dim3(256), 0, stream,
                       bwr, bwi, cwr, cwi, wbhi, wblo, wchi);
    hipLaunchKernelGGL(k_g1,    dim3(ROWS / 128), dim3(256), 0, stream,
                       xr, xi, dtw, dtb, wbhi, wblo, bxr, bxi, dt_mag, dt_ph);
    hipLaunchKernelGGL(k_scanA, dim3((NCHAIN * CH) / 256), dim3(256), 0, stream,
                       dt_mag, dt_ph, logAm, Aph, bxr, bxi, trans);
    hipLaunchKernelGGL(k_scanB, dim3(NCHAIN / 256), dim3(256), 0, stream,
                       trans, hstart);
    hipLaunchKernelGGL(k_sg2,   dim3((B_ * G_) * 16), dim3(256), 0, stream,
                       bxr, bxi, dt_mag, dt_ph, logAm, Aph, hstart, wchi, out);
}

// Round 4
// 163.718 us; speedup vs baseline: 2.2222x; 1.0632x over previous
//
#include <hip/hip_runtime.h>
#include <math.h>

#define B_ 4
#define S_ 2048
#define G_ 8
#define D_ 128
#define N_ 64
#define ROWS (B_*S_*G_)      // 65536
#define CH 64
#define CLEN 32
#define NCHAIN (B_*G_*N_)    // 2048
#define YOFF (ROWS*D_)       // 8388608

typedef short bf16x8 __attribute__((ext_vector_type(8)));
typedef float f32x4  __attribute__((ext_vector_type(4)));
#define MFMA16(a,b,c) __builtin_amdgcn_mfma_f32_16x16x32_bf16(a,b,c,0,0,0)

__device__ __forceinline__ unsigned short bf16_rtne(float f) {
    unsigned u = __float_as_uint(f);
    unsigned r = (u + 0x7FFFu + ((u >> 16) & 1u)) >> 16;
    return (unsigned short)r;
}
__device__ __forceinline__ void split_bf16(float f, unsigned short &hi, unsigned short &lo) {
    hi = bf16_rtne(f);
    float hif = __uint_as_float(((unsigned)hi) << 16);
    lo = bf16_rtne(f - hif);
}
__device__ __forceinline__ void split4(float4 v, uint2 &hi2, uint2 &lo2) {
    unsigned short h0,h1,h2,h3,l0,l1,l2,l3;
    split_bf16(v.x,h0,l0); split_bf16(v.y,h1,l1);
    split_bf16(v.z,h2,l2); split_bf16(v.w,h3,l3);
    hi2 = make_uint2((unsigned)h0 | ((unsigned)h1<<16), (unsigned)h2 | ((unsigned)h3<<16));
    lo2 = make_uint2((unsigned)l0 | ((unsigned)l1<<16), (unsigned)l2 | ((unsigned)l3<<16));
}
__device__ __forceinline__ float dot4(float4 a, float4 b) {
    return fmaf(a.x,b.x, fmaf(a.y,b.y, fmaf(a.z,b.z, a.w*b.w)));
}

// ============ k_prep: pre-split weights into MFMA fragment order ============
__global__ __launch_bounds__(256) void k_prep(
    const float* __restrict__ bwr, const float* __restrict__ bwi,
    const float* __restrict__ cwr, const float* __restrict__ cwi,
    unsigned short* __restrict__ wbhi, unsigned short* __restrict__ wblo,
    unsigned short* __restrict__ wchi)
{
    int tid = blockIdx.x * 256 + threadIdx.x;   // [0, 8192)
    if (tid < 4096) {
        int f = tid;
        int lane = f & 63, ks = (f >> 6) & 7, nt = (f >> 9) & 1, w = f >> 10;
        int l15 = lane & 15, quad = lane >> 4;
        int n = w * 32 + nt * 16 + l15;
        int k0 = ks * 32 + quad * 8;
        const float* src; float sgn = 1.f;
        if (n < 64) {
            if (k0 < 128) src = bwr + n * 128 + k0;
            else        { src = bwi + n * 128 + (k0 - 128); sgn = -1.f; }
        } else {
            if (k0 < 128) src = bwi + (n - 64) * 128 + k0;
            else          src = bwr + (n - 64) * 128 + (k0 - 128);
        }
        float4 v0 = *(const float4*)src;
        float4 v1 = *(const float4*)(src + 4);
        float vv[8] = {v0.x,v0.y,v0.z,v0.w,v1.x,v1.y,v1.z,v1.w};
        unsigned short h[8], l[8];
        #pragma unroll
        for (int j = 0; j < 8; j++) split_bf16(vv[j] * sgn, h[j], l[j]);
        #pragma unroll
        for (int j = 0; j < 8; j++) { wbhi[f*8+j] = h[j]; wblo[f*8+j] = l[j]; }
    } else {
        int f = tid - 4096;
        int lane = f & 63, ks = (f >> 6) & 3, nt = (f >> 8) & 3, w = f >> 10;
        int l15 = lane & 15, quad = lane >> 4;
        int n = w * 64 + nt * 16 + l15;
        int d = (n < 128) ? n : (n - 128);
        int k0 = ks * 32 + quad * 8;
        const float* src; float sgn = 1.f;
        if (n < 128) {
            if (k0 < 64) src = cwr + d * 64 + k0;
            else       { src = cwi + d * 64 + (k0 - 64); sgn = -1.f; }
        } else {
            if (k0 < 64) src = cwi + d * 64 + k0;
            else         src = cwr + d * 64 + (k0 - 64);
        }
        float4 v0 = *(const float4*)src;
        float4 v1 = *(const float4*)(src + 4);
        float vv[8] = {v0.x,v0.y,v0.z,v0.w,v1.x,v1.y,v1.z,v1.w};
        unsigned short h[8], l[8];
        #pragma unroll
        for (int j = 0; j < 8; j++) split_bf16(vv[j] * sgn, h[j], l[j]);
        #pragma unroll
        for (int j = 0; j < 8; j++) wchi[f*8+j] = h[j];
    }
}

// ============ G1: fused dt + Bx GEMM + chunk-transition compose =============
// block = (bg, cq): 4 chunks of 32 timesteps of one (b,g). Rows at stride G.
// After MFMA, Bx parked in LDS (stride 132 -> 2-way banks only) and waves 0/1
// compose the per-chunk transition (A,B), writing trans directly (scanA fused).
#define LDK1 280
__global__ __launch_bounds__(256, 2) void k_g1(
    const float* __restrict__ xr, const float* __restrict__ xi,
    const float* __restrict__ dtw, const float* __restrict__ dtb,
    const float* __restrict__ logAm, const float* __restrict__ Aph,
    const unsigned short* __restrict__ wbhi, const unsigned short* __restrict__ wblo,
    float* __restrict__ bxr, float* __restrict__ bxi,
    float* __restrict__ dt_mag, float* __restrict__ dt_ph,
    float4* __restrict__ trans)
{
    __shared__ __align__(16) unsigned short Ahi[32 * LDK1];
    __shared__ __align__(16) unsigned short Alo[32 * LDK1];
    __shared__ float dms[32], dps[32];
    __shared__ float4 comb[64];
    float* bxs = (float*)Ahi;   // reused after MFMA reads (16.9KB <= 17.9KB)
    const int t = threadIdx.x;
    const int lane = t & 63, w = t >> 6;
    const int l15 = lane & 15, quad = lane >> 4;
    const int bg = blockIdx.x >> 4, cq = blockIdx.x & 15;
    const int g = bg & 7, b = bg >> 3;

    // W fragments (precomputed, coalesced 16B loads)
    bf16x8 wh[2][8], wl[2][8];
    #pragma unroll
    for (int nt = 0; nt < 2; nt++)
        #pragma unroll
        for (int ks = 0; ks < 8; ks++) {
            int idx = ((w * 2 + nt) * 8 + ks) * 64 + lane;
            wh[nt][ks] = ((const bf16x8*)wbhi)[idx];
            wl[nt][ks] = ((const bf16x8*)wblo)[idx];
        }

    const int kq = t & 31, k4 = kq * 4;
    float4 w0r = *(const float4*)(dtw + k4);
    float4 w0i = *(const float4*)(dtw + 128 + k4);
    float4 w1r = *(const float4*)(dtw + 256 + k4);
    float4 w1i = *(const float4*)(dtw + 384 + k4);
    float b0 = dtb[0], b1 = dtb[1];
    float nla = -logf(1.0f + __expf(logAm[g * N_ + lane]));
    float aph = Aph[g * N_ + lane];

    for (int it = 0; it < 4; it++) {
        __syncthreads();   // protect bxs/comb reads from new staging writes
        const int c  = cq * 4 + it;
        const int s0 = c * CLEN;
        const float* xrb = xr + ((size_t)(b * S_ + s0) * G_ + g) * 128;
        const float* xib = xi + ((size_t)(b * S_ + s0) * G_ + g) * 128;
        float pm[4], pp[4];
        #pragma unroll
        for (int i = 0; i < 4; i++) {
            int f = t + 256 * i;
            int m = f >> 5, kk = f & 31;
            float4 a  = ((const float4*)(xrb + m * 1024))[kk];
            float4 bb = ((const float4*)(xib + m * 1024))[kk];
            uint2 h2, l2;
            split4(a, h2, l2);
            *(uint2*)&Ahi[m * LDK1 + kk * 4] = h2;
            *(uint2*)&Alo[m * LDK1 + kk * 4] = l2;
            split4(bb, h2, l2);
            *(uint2*)&Ahi[m * LDK1 + 128 + kk * 4] = h2;
            *(uint2*)&Alo[m * LDK1 + 128 + kk * 4] = l2;
            pm[i] = dot4(a, w0r) + dot4(bb, w0i);
            pp[i] = dot4(a, w1r) + dot4(bb, w1i);
        }
        #pragma unroll
        for (int i = 0; i < 4; i++) {
            float vm = pm[i], vp = pp[i];
            #pragma unroll
            for (int msk = 16; msk >= 1; msk >>= 1) {
                vm += __shfl_xor(vm, msk);
                vp += __shfl_xor(vp, msk);
            }
            if ((t & 31) == 0) {
                int m = (t >> 5) + 8 * i;
                float dm = fminf(fmaxf(__expf(vm + b0), 1e-4f), 2.0f);
                float dp = fminf(fmaxf(__expf(vp + b1), 1e-4f), 2.0f);
                dms[m] = dm; dps[m] = dp;
                int row = (b * S_ + s0 + m) * G_ + g;
                dt_mag[row] = dm; dt_ph[row] = dp;
            }
        }
        __syncthreads();

        f32x4 acc[2][2];
        #pragma unroll
        for (int a = 0; a < 2; a++)
            #pragma unroll
            for (int bq = 0; bq < 2; bq++)
                acc[a][bq] = (f32x4){0.f, 0.f, 0.f, 0.f};
        #pragma unroll
        for (int ms = 0; ms < 2; ms++) {
            int arow = (ms * 16 + l15) * LDK1 + quad * 8;
            #pragma unroll
            for (int ks = 0; ks < 8; ks++) {
                bf16x8 ah = *(const bf16x8*)&Ahi[arow + ks * 32];
                bf16x8 al = *(const bf16x8*)&Alo[arow + ks * 32];
                #pragma unroll
                for (int nt = 0; nt < 2; nt++) {
                    acc[ms][nt] = MFMA16(al, wh[nt][ks], acc[ms][nt]);
                    acc[ms][nt] = MFMA16(ah, wl[nt][ks], acc[ms][nt]);
                    acc[ms][nt] = MFMA16(ah, wh[nt][ks], acc[ms][nt]);
                }
            }
        }
        __syncthreads();   // staging reads done; Ahi region becomes bxs

        // store Bx to global + LDS (scaled by dt_mag)
        #pragma unroll
        for (int ms = 0; ms < 2; ms++)
            #pragma unroll
            for (int nt = 0; nt < 2; nt++) {
                int n = w * 32 + nt * 16 + l15;
                float* dstg = (n < 64) ? bxr : bxi;
                int nn = n & 63;
                #pragma unroll
                for (int r = 0; r < 4; r++) {
                    int m = ms * 16 + quad * 4 + r;
                    float v = acc[ms][nt][r] * dms[m];
                    dstg[((b * S_ + s0 + m) * G_ + g) * 64 + nn] = v;
                    bxs[m * 132 + n] = v;
                }
            }
        __syncthreads();

        // compose chunk transition: wave 0 = steps 0..15, wave 1 = 16..31
        float Ar = 1.f, Ai = 0.f, Br = 0.f, Bi = 0.f;
        if (w < 2) {
            int base = w * 16;
            #pragma unroll
            for (int tt = 0; tt < 16; tt++) {
                int m = base + tt;
                float dm = dms[m], dp = dps[m];
                float am  = __expf(dm * nla);
                float ang = dp * aph;
                float cr = am * __cosf(ang), ci = am * __sinf(ang);
                float vr = bxs[m * 132 + lane], vi = bxs[m * 132 + 64 + lane];
                float nAr = cr * Ar - ci * Ai;
                float nAi = cr * Ai + ci * Ar;
                float nBr = cr * Br - ci * Bi + vr;
                float nBi = cr * Bi + ci * Br + vi;
                Ar = nAr; Ai = nAi; Br = nBr; Bi = nBi;
            }
            if (w == 0) comb[lane] = make_float4(Ar, Ai, Br, Bi);
        }
        __syncthreads();
        if (w == 1) {
            float4 c0 = comb[lane];
            float fAr = Ar * c0.x - Ai * c0.y;
            float fAi = Ar * c0.y + Ai * c0.x;
            float fBr = Ar * c0.z - Ai * c0.w + Br;
            float fBi = Ar * c0.w + Ai * c0.z + Bi;
            trans[(bg * CH + c) * 64 + lane] = make_float4(fAr, fAi, fBr, fBi);
        }
    }
}

// ============ scanB2: parallel chunk-level combine ==========================
// 8 lanes per chain: lane j composes segment j's 8 chunk-prefixes (independent
// loads), segment h walked with renorm via shuffles, then 8 chunk-start h out.
__global__ __launch_bounds__(256) void k_scanB2(const float4* __restrict__ trans,
    float2* __restrict__ hstart)
{
    int w = threadIdx.x >> 6, lane = threadIdx.x & 63;
    int W = blockIdx.x * 4 + w;              // [0,256)
    int bg = W >> 3;
    int n  = ((W & 7) << 3) + (lane & 7);
    int j  = lane >> 3;                       // segment index
    float pAr[8], pAi[8], pBr[8], pBi[8];
    float Ar = 1.f, Ai = 0.f, Br = 0.f, Bi = 0.f;
    const float4* tp = trans + (bg * CH + j * 8) * 64 + n;
    #pragma unroll
    for (int k = 0; k < 8; k++) {
        pAr[k] = Ar; pAi[k] = Ai; pBr[k] = Br; pBi[k] = Bi;
        float4 T = tp[k * 64];
        float nAr = T.x * Ar - T.y * Ai;
        float nAi = T.x * Ai + T.y * Ar;
        float nBr = T.x * Br - T.y * Bi + T.z;
        float nBi = T.x * Bi + T.y * Br + T.w;
        Ar = nAr; Ai = nAi; Br = nBr; Bi = nBi;
    }
    // walk segments sequentially (renorm at every segment end = every 8 chunks)
    float hr = 0.f, hi = 0.f, mhr = 0.f, mhi = 0.f;
    #pragma unroll
    for (int j2 = 0; j2 < 8; j2++) {
        if (j2 == j) { mhr = hr; mhi = hi; }
        int src = j2 * 8 + (lane & 7);
        float sAr = __shfl(Ar, src), sAi = __shfl(Ai, src);
        float sBr = __shfl(Br, src), sBi = __shfl(Bi, src);
        float nr = sAr * hr - sAi * hi + sBr;
        float ni = sAr * hi + sAi * hr + sBi;
        float nrm = sqrtf(nr * nr + ni * ni + 1e-8f);
        float sc = fminf(nrm, 100.f) / nrm;
        hr = nr * sc; hi = ni * sc;
    }
    float2* hp = hstart + (bg * CH + j * 8) * 64 + n;
    #pragma unroll
    for (int k = 0; k < 8; k++) {
        float hsr = pAr[k] * mhr - pAi[k] * mhi + pBr[k];
        float hsi = pAr[k] * mhi + pAi[k] * mhr + pBi[k];
        hp[k * 64] = make_float2(hsr, hsi);
    }
}

// ============ SG2: fused scanC + y GEMM =====================================
#define LDK2 152
__global__ __launch_bounds__(256, 2) void k_sg2(
    const float* __restrict__ bxr, const float* __restrict__ bxi,
    const float* __restrict__ dt_mag, const float* __restrict__ dt_ph,
    const float* __restrict__ logAm, const float* __restrict__ Aph,
    const float2* __restrict__ hstart,
    const unsigned short* __restrict__ wchi,
    float* __restrict__ out)
{
    __shared__ __align__(16) unsigned short Ahi[128 * LDK2];
    __shared__ __align__(16) unsigned short Alo[128 * LDK2];
    const int t = threadIdx.x;
    const int lane = t & 63, w = t >> 6;
    const int l15 = lane & 15, quad = lane >> 4;
    const int bg = blockIdx.x >> 4, cq = blockIdx.x & 15;
    const int g = bg & 7, b = bg >> 3;

    bf16x8 wc[4][4];
    #pragma unroll
    for (int nt = 0; nt < 4; nt++)
        #pragma unroll
        for (int ks = 0; ks < 4; ks++)
            wc[nt][ks] = ((const bf16x8*)wchi)[((w * 4 + nt) * 4 + ks) * 64 + lane];

    {
        const int n = lane;
        const int c = cq * 4 + w;
        float nla = -logf(1.0f + __expf(logAm[g * N_ + n]));
        float aph = Aph[g * N_ + n];
        float2 h0 = hstart[(bg * CH + c) * 64 + n];
        float hr = h0.x, hi = h0.y;
        const bool rn = ((c & 7) == 7);
        const int rowbase = (b * S_ + c * CLEN) * G_ + g;
        #pragma unroll 8
        for (int tt = 0; tt < CLEN; tt++) {
            int row = rowbase + tt * G_;
            float dm = dt_mag[row], dp = dt_ph[row];
            float am  = __expf(dm * nla);
            float ang = dp * aph;
            float cr = am * __cosf(ang), ci = am * __sinf(ang);
            float vr = bxr[row * N_ + n], vi = bxi[row * N_ + n];
            float nr = cr * hr - ci * hi + vr;
            float ni = cr * hi + ci * hr + vi;
            if (rn && tt == CLEN - 1) {
                float nrm = sqrtf(nr * nr + ni * ni + 1e-8f);
                float scale = fminf(nrm, 100.0f) / nrm;
                nr *= scale; ni *= scale;
            }
            hr = nr; hi = ni;
            int m = w * 32 + tt;
            unsigned short hh, hl;
            split_bf16(hr, hh, hl);
            Ahi[m * LDK2 + n] = hh;  Alo[m * LDK2 + n] = hl;
            split_bf16(hi, hh, hl);
            Ahi[m * LDK2 + 64 + n] = hh;  Alo[m * LDK2 + 64 + n] = hl;
        }
    }
    __syncthreads();

    #pragma unroll
    for (int mh = 0; mh < 2; mh++) {
        f32x4 acc[4][4];
        #pragma unroll
        for (int a = 0; a < 4; a++)
            #pragma unroll
            for (int bq = 0; bq < 4; bq++)
                acc[a][bq] = (f32x4){0.f, 0.f, 0.f, 0.f};
        #pragma unroll
        for (int ms = 0; ms < 4; ms++) {
            int arow = (mh * 64 + ms * 16 + l15) * LDK2 + quad * 8;
            #pragma unroll
            for (int ks = 0; ks < 4; ks++) {
                bf16x8 ah = *(const bf16x8*)&Ahi[arow + ks * 32];
                bf16x8 al = *(const bf16x8*)&Alo[arow + ks * 32];
                #pragma unroll
                for (int nt = 0; nt < 4; nt++) {
                    acc[ms][nt] = MFMA16(al, wc[nt][ks], acc[ms][nt]);
                    acc[ms][nt] = MFMA16(ah, wc[nt][ks], acc[ms][nt]);
                }
            }
        }
        #pragma unroll
        for (int ms = 0; ms < 4; ms++)
            #pragma unroll
            for (int nt = 0; nt < 4; nt++) {
                int nn = w * 64 + nt * 16 + l15;
                float* dst = (nn < 128) ? (out + nn) : (out + YOFF + (nn - 128));
                #pragma unroll
                for (int r = 0; r < 4; r++) {
                    int m_local = mh * 64 + ms * 16 + quad * 4 + r;
                    int cc = m_local >> 5, tt2 = m_local & 31;
                    int srow = (b * S_ + (cq * 4 + cc) * CLEN + tt2) * G_ + g;
                    dst[srow * 128] = acc[ms][nt][r];
                }
            }
    }
}

extern "C" void kernel_launch(void* const* d_in, const int* in_sizes, int n_in,
                              void* d_out, int out_size, void* d_ws, size_t ws_size,
                              hipStream_t stream) {
    (void)in_sizes; (void)n_in; (void)out_size; (void)ws_size;
    const float* xr    = (const float*)d_in[0];
    const float* xi    = (const float*)d_in[1];
    const float* logAm = (const float*)d_in[2];
    const float* Aph   = (const float*)d_in[3];
    const float* bwr   = (const float*)d_in[4];
    const float* bwi   = (const float*)d_in[5];
    const float* cwr   = (const float*)d_in[6];
    const float* cwi   = (const float*)d_in[7];
    const float* dtw   = (const float*)d_in[8];
    const float* dtb   = (const float*)d_in[9];
    float* out = (float*)d_out;
    float* ws  = (float*)d_ws;

    float*  dt_mag = ws;                      // 65536
    float*  dt_ph  = ws + 65536;              // 65536
    float*  bxr    = ws + 131072;             // 4194304
    float*  bxi    = bxr + 4194304;           // 4194304
    float4* trans  = (float4*)(ws + 8519680); // 131072 float4
    float2* hstart = (float2*)(ws + 9043968); // 131072 float2
    unsigned short* wbhi = (unsigned short*)(ws + 9306112); // 32768 shorts
    unsigned short* wblo = wbhi + 32768;
    unsigned short* wchi = wblo + 32768;

    hipLaunchKernelGGL(k_prep,   dim3(32), dim3(256), 0, stream,
                       bwr, bwi, cwr, cwi, wbhi, wblo, wchi);
    hipLaunchKernelGGL(k_g1,     dim3((B_ * G_) * 16), dim3(256), 0, stream,
                       xr, xi, dtw, dtb, logAm, Aph, wbhi, wblo,
                       bxr, bxi, dt_mag, dt_ph, trans);
    hipLaunchKernelGGL(k_scanB2, dim3(64), dim3(256), 0, stream,
                       trans, hstart);
    hipLaunchKernelGGL(k_sg2,    dim3((B_ * G_) * 16), dim3(256), 0, stream,
                       bxr, bxi, dt_mag, dt_ph, logAm, Aph, hstart, wchi, out);
}